// Round 19
// baseline (495.661 us; speedup 1.0000x reference)
//
#include <hip/hip_runtime.h>
#include <hip/hip_bf16.h>

#define NB  2
#define SS  2048
#define HH  4096
#define NH  32
#define NKV 8
#define HD  128
#define MR  (NB*SS)   // 4096 token rows

typedef __bf16 bf16x8 __attribute__((ext_vector_type(8)));
typedef float  f32x4  __attribute__((ext_vector_type(4)));
typedef float  f32x16 __attribute__((ext_vector_type(16)));
using bf16 = __hip_bfloat16;

__device__ __forceinline__ f32x4 mfma16(bf16x8 a, bf16x8 b, f32x4 c) {
  return __builtin_amdgcn_mfma_f32_16x16x32_bf16(a, b, c, 0, 0, 0);
}
__device__ __forceinline__ f32x16 mfma32(bf16x8 a, bf16x8 b, f32x16 c) {
  return __builtin_amdgcn_mfma_f32_32x32x16_bf16(a, b, c, 0, 0, 0);
}
__device__ __forceinline__ unsigned cvtpk(float lo, float hi) {
  unsigned r; asm("v_cvt_pk_bf16_f32 %0, %1, %2" : "=v"(r) : "v"(lo), "v"(hi));
  return r;
}
// Used ONLY with two genuinely-distinct producer values (cvtpk results,
// >=2 instrs apart). Round 10/11 lesson: no self-copy reduces.
__device__ __forceinline__ void swap32(unsigned &a, unsigned &b) {
  asm volatile("v_permlane32_swap_b32 %0, %1" : "+v"(a), "+v"(b));
}
__device__ __forceinline__ float fexp2(float x) {
  float r; asm("v_exp_f32 %0, %1" : "=v"(r) : "v"(x)); return r;
}

typedef const __attribute__((address_space(1))) void gv_t;
typedef __attribute__((address_space(3))) void lv_t;
__device__ __forceinline__ void gload16(const void* g, void* l) {
  __builtin_amdgcn_global_load_lds((gv_t*)g, (lv_t*)l, 16, 0, 0);
}
#define CFENCE asm volatile("" ::: "memory")

// --------------------------------- fp32 -> bf16, per-block segments, 4x MLP
__device__ __forceinline__ void cvtstore(bf16* __restrict__ d, unsigned u,
                                         float4 v)
{
  __hip_bfloat16 b0 = __float2bfloat16(v.x);
  __hip_bfloat16 b1 = __float2bfloat16(v.y);
  __hip_bfloat16 b2 = __float2bfloat16(v.z);
  __hip_bfloat16 b3 = __float2bfloat16(v.w);
  ushort4 o;
  o.x = *reinterpret_cast<unsigned short*>(&b0);
  o.y = *reinterpret_cast<unsigned short*>(&b1);
  o.z = *reinterpret_cast<unsigned short*>(&b2);
  o.w = *reinterpret_cast<unsigned short*>(&b3);
  *(ushort4*)((unsigned short*)d + (size_t)u*4) = o;
}
__device__ __forceinline__ void cvtseg(const float* __restrict__ s,
                                       bf16* __restrict__ d,
                                       unsigned n, unsigned u0, unsigned T)
{
  unsigned u = u0;
  for (; u + 3*T < n; u += 4*T) {      // 4 independent loads in flight
    float4 v0 = *(const float4*)(s + (size_t)u*4);
    float4 v1 = *(const float4*)(s + (size_t)(u + T)*4);
    float4 v2 = *(const float4*)(s + (size_t)(u + 2*T)*4);
    float4 v3 = *(const float4*)(s + (size_t)(u + 3*T)*4);
    cvtstore(d, u, v0);
    cvtstore(d, u + T, v1);
    cvtstore(d, u + 2*T, v2);
    cvtstore(d, u + 3*T, v3);
  }
  for (; u < n; u += T) {
    float4 v = *(const float4*)(s + (size_t)u*4);
    cvtstore(d, u, v);
  }
}
// blocks: x 600 | wq 600 | wk 150 | wv 150 | wo 600  (uniform branch/block)
__global__ __launch_bounds__(256) void f2b5(
    const float* __restrict__ s0, const float* __restrict__ s1,
    const float* __restrict__ s2, const float* __restrict__ s3,
    const float* __restrict__ s4,
    bf16* __restrict__ d0, bf16* __restrict__ d1,
    bf16* __restrict__ d2, bf16* __restrict__ d3, bf16* __restrict__ d4)
{
  const int blk = blockIdx.x, tid = threadIdx.x;
  if (blk < 600)
    cvtseg(s0, d0, 4194304u, (unsigned)(blk*256 + tid), 153600u);
  else if (blk < 1200)
    cvtseg(s1, d1, 4194304u, (unsigned)((blk - 600)*256 + tid), 153600u);
  else if (blk < 1350)
    cvtseg(s2, d2, 1048576u, (unsigned)((blk - 1200)*256 + tid), 38400u);
  else if (blk < 1500)
    cvtseg(s3, d3, 1048576u, (unsigned)((blk - 1350)*256 + tid), 38400u);
  else
    cvtseg(s4, d4, 4194304u, (unsigned)((blk - 1500)*256 + tid), 153600u);
}

// ------------------------------------------------- C[M,N] = A[M,K] @ Bt[N,K]^T
// Round-14 measured-best body (45.5-47% MfmaUtil, 0 conflicts): 256x256 tile,
// BK=64, 8 waves (2M x 4N, wave 128x64), 512 thr, mfma 16x16x32, 8-phase/
// 2-K-tile counted-vmcnt schedule. LOCAL OPTIMUM (r12/r15/m97 all regress).
template<typename OutT>
__device__ __forceinline__ void gemm256_body(
    bf16* lds, const bf16* __restrict__ A, const bf16* __restrict__ Bt,
    OutT* __restrict__ C, int bid, int N, int K, int tilesX)
{
  const int cpx = 32;                      // 256 tiles / 8 XCDs
  const int wg  = (bid & 7)*cpx + (bid >> 3);
  const int m0 = (wg / tilesX) * 256, n0 = (wg % tilesX) * 256;

  const int tid = threadIdx.x;
  const int l = tid & 63;
  const int l15 = l & 15, lhi = l >> 4;
  const int wid = tid >> 6;
  const int wr = wid >> 2, wc = wid & 3;   // wave tile 128x64

  const int srow = tid >> 2;
  const int sps  = tid & 3;
  const int sls  = (sps - (srow >> 1)) & 3;
  const bf16* ga0 = A  + (size_t)(m0 + srow)*K       + sls*8;
  const bf16* ga1 = A  + (size_t)(m0 + srow + 128)*K + sls*8;
  const bf16* gb0 = Bt + (size_t)(n0 + srow)*K       + sls*8;
  const bf16* gb1 = Bt + (size_t)(n0 + srow + 128)*K + sls*8;
  const int ldst = tid*8;

#define REG(buf, mat, ks) (&lds[(((buf)*2 + (mat))*2 + (ks))*8192])
#define STG_A(buf, ks, kofs) do {                                 \
    gload16(ga0 + (kofs), REG(buf,0,ks) + ldst);                  \
    gload16(ga1 + (kofs), REG(buf,0,ks) + ldst + 4096);           \
  } while (0)
#define STG_B(buf, ks, kofs) do {                                 \
    gload16(gb0 + (kofs), REG(buf,1,ks) + ldst);                  \
    gload16(gb1 + (kofs), REG(buf,1,ks) + ldst + 4096);           \
  } while (0)

  f32x4 acc[8][4];
  #pragma unroll
  for (int fm = 0; fm < 8; ++fm)
    #pragma unroll
    for (int fn = 0; fn < 4; ++fn)
      #pragma unroll
      for (int e = 0; e < 4; ++e) acc[fm][fn][e] = 0.f;

  const int arow = wr*128 + l15;
  const int brow = wc*64  + l15;
  const int psl  = (lhi + (l15 >> 1)) & 3;

  bf16x8 bv[4];

#define PHASE(PB, KS, FMH, RB, STG, WN) do {                               \
    const bf16* Ar_ = REG(PB, 0, KS);                                      \
    const bf16* Br_ = REG(PB, 1, KS);                                      \
    bf16x8 af[4];                                                          \
    for (int fm = 0; fm < 4; ++fm)                                         \
      af[fm] = *(const bf16x8*)(Ar_ + (arow + (FMH)*64 + fm*16)*32 + psl*8); \
    if (RB) {                                                              \
      for (int fn = 0; fn < 4; ++fn)                                       \
        bv[fn] = *(const bf16x8*)(Br_ + (brow + fn*16)*32 + psl*8);        \
    }                                                                      \
    STG;                                                                   \
    CFENCE;                                                                \
    __builtin_amdgcn_s_barrier();                                          \
    __builtin_amdgcn_s_setprio(1);                                         \
    for (int fm = 0; fm < 4; ++fm)                                         \
      for (int fn = 0; fn < 4; ++fn)                                       \
        acc[(FMH)*4 + fm][fn] = mfma16(af[fm], bv[fn], acc[(FMH)*4 + fm][fn]); \
    __builtin_amdgcn_s_setprio(0);                                         \
    if ((WN) == 6)      asm volatile("s_waitcnt vmcnt(6)" ::: "memory");   \
    else if ((WN) == 0) asm volatile("s_waitcnt vmcnt(0)" ::: "memory");   \
    __builtin_amdgcn_s_barrier();                                          \
    CFENCE;                                                                \
  } while (0)

  const int nt = K >> 6;

  STG_A(0, 0, 0);  STG_B(0, 0, 0);  STG_A(0, 1, 32);  STG_B(0, 1, 32);
  STG_A(1, 0, 64); STG_B(1, 0, 64); STG_B(1, 1, 96);
  asm volatile("s_waitcnt vmcnt(6)" ::: "memory");
  __builtin_amdgcn_s_barrier();
  CFENCE;

  for (int i = 0; i < (nt >> 1) - 1; ++i) {
    const int t  = i << 1;
    const int k1 = ((t + 1) << 6) + 32;
    const int k2 = (t + 2) << 6;
    const int k3 = (t + 3) << 6;
    PHASE(0, 0, 0, true,  STG_A(1, 1, k1),      -1);
    PHASE(0, 0, 1, false, STG_B(0, 0, k2),      -1);
    PHASE(0, 1, 0, true,  STG_A(0, 0, k2),      -1);
    PHASE(0, 1, 1, false, STG_B(0, 1, k2 + 32),  6);
    PHASE(1, 0, 0, true,  STG_A(0, 1, k2 + 32), -1);
    PHASE(1, 0, 1, false, STG_B(1, 0, k3),      -1);
    PHASE(1, 1, 0, true,  STG_A(1, 0, k3),      -1);
    PHASE(1, 1, 1, false, STG_B(1, 1, k3 + 32),  6);
  }
  {
    const int k1 = ((nt - 1) << 6) + 32;
    PHASE(0, 0, 0, true,  STG_A(1, 1, k1), -1);
    PHASE(0, 0, 1, false, (void)0,         -1);
    PHASE(0, 1, 0, true,  (void)0,         -1);
    PHASE(0, 1, 1, false, (void)0,          0);
    PHASE(1, 0, 0, true,  (void)0,         -1);
    PHASE(1, 0, 1, false, (void)0,         -1);
    PHASE(1, 1, 0, true,  (void)0,         -1);
    PHASE(1, 1, 1, false, (void)0,         -1);
  }
#undef PHASE
#undef STG_A
#undef STG_B
#undef REG

  #pragma unroll
  for (int fm = 0; fm < 8; ++fm) {
    const int crow = m0 + wr*128 + fm*16 + lhi*4;
    #pragma unroll
    for (int fn = 0; fn < 4; ++fn) {
      const int ccol = n0 + wc*64 + fn*16 + l15;
      #pragma unroll
      for (int j = 0; j < 4; ++j) {
        if constexpr (sizeof(OutT) == 2)
          C[(size_t)(crow + j)*N + ccol] = __float2bfloat16(acc[fm][fn][j]);
        else
          C[(size_t)(crow + j)*N + ccol] = acc[fm][fn][j];
      }
    }
  }
}

// ------------------------------------------------- 128x256-tile GEMM body
// (KV-proj; round-9 proven, 0 conflicts)
__device__ __forceinline__ void gemm128n_body(
    bf16* lds, const bf16* __restrict__ A, const bf16* __restrict__ Bt,
    bf16* __restrict__ C, int bid, int N, int K, int tilesX)
{
  const int cpx = 32;
  const int wg  = (bid & 7)*cpx + (bid >> 3);
  const int m0 = (wg / tilesX) * 128, n0 = (wg % tilesX) * 256;

  const int tid = threadIdx.x;
  const int l = tid & 63;
  const int l15 = l & 15, lhi = l >> 4;
  const int wid = tid >> 6;
  const int wr = wid >> 2, wc = wid & 3;   // wave tile 64x64

  const int srow = tid >> 2;
  const int sps  = tid & 3;
  const int sls  = (sps - (srow >> 1)) & 3;
  const bf16* gaA = A  + (size_t)(m0 + srow)*K       + sls*8;
  const bf16* gb0 = Bt + (size_t)(n0 + srow)*K       + sls*8;
  const bf16* gb1 = Bt + (size_t)(n0 + srow + 128)*K + sls*8;
  const int ldst = tid*8;

#define REGA(buf, ks) (&lds[((buf)*2 + (ks))*12288])
#define REGB(buf, ks) (&lds[((buf)*2 + (ks))*12288 + 4096])
#define STGKA(buf, ks, kofs) gload16(gaA + (kofs), REGA(buf,ks) + ldst)
#define STGKB(buf, ks, kofs) do {                                 \
    gload16(gb0 + (kofs), REGB(buf,ks) + ldst);                   \
    gload16(gb1 + (kofs), REGB(buf,ks) + ldst + 4096);            \
  } while (0)

  f32x4 acc[4][4];
  #pragma unroll
  for (int fm = 0; fm < 4; ++fm)
    #pragma unroll
    for (int fn = 0; fn < 4; ++fn)
      #pragma unroll
      for (int e = 0; e < 4; ++e) acc[fm][fn][e] = 0.f;

  const int arow = wr*64 + l15;
  const int brow = wc*64 + l15;
  const int psl  = (lhi + (l15 >> 1)) & 3;

#define PHASEK(PB, KS, STG, WN) do {                                       \
    const bf16* Ar_ = REGA(PB, KS);                                        \
    const bf16* Br_ = REGB(PB, KS);                                        \
    bf16x8 af[4], bv[4];                                                   \
    for (int fm = 0; fm < 4; ++fm)                                         \
      af[fm] = *(const bf16x8*)(Ar_ + (arow + fm*16)*32 + psl*8);          \
    for (int fn = 0; fn < 4; ++fn)                                         \
      bv[fn] = *(const bf16x8*)(Br_ + (brow + fn*16)*32 + psl*8);          \
    STG;                                                                   \
    CFENCE;                                                                \
    __builtin_amdgcn_s_barrier();                                          \
    __builtin_amdgcn_s_setprio(1);                                         \
    for (int fm = 0; fm < 4; ++fm)                                         \
      for (int fn = 0; fn < 4; ++fn)                                       \
        acc[fm][fn] = mfma16(af[fm], bv[fn], acc[fm][fn]);                 \
    __builtin_amdgcn_s_setprio(0);                                         \
    if ((WN) == 6)      asm volatile("s_waitcnt vmcnt(6)" ::: "memory");   \
    else if ((WN) == 0) asm volatile("s_waitcnt vmcnt(0)" ::: "memory");   \
    __builtin_amdgcn_s_barrier();                                          \
    CFENCE;                                                                \
  } while (0)

  const int nt = K >> 6;

  STGKB(0, 0, 0);  STGKA(0, 0, 0);  STGKB(0, 1, 32);  STGKA(0, 1, 32);
  STGKB(1, 0, 64); STGKA(1, 0, 64); STGKB(1, 1, 96);  STGKA(1, 1, 96);
  asm volatile("s_waitcnt vmcnt(6)" ::: "memory");
  __builtin_amdgcn_s_barrier();
  CFENCE;

  for (int i = 0; i < (nt >> 1) - 1; ++i) {
    const int t  = i << 1;
    const int k2 = (t + 2) << 6;
    const int k3 = (t + 3) << 6;
    PHASEK(0, 0, { STGKB(0, 0, k2);      STGKA(0, 0, k2);      }, -1);
    PHASEK(0, 1, { STGKB(0, 1, k2 + 32); STGKA(0, 1, k2 + 32); },  6);
    PHASEK(1, 0, { STGKB(1, 0, k3);      STGKA(1, 0, k3);      }, -1);
    PHASEK(1, 1, { STGKB(1, 1, k3 + 32); STGKA(1, 1, k3 + 32); },  6);
  }
  {
    PHASEK(0, 0, (void)0, -1);
    PHASEK(0, 1, (void)0,  0);
    PHASEK(1, 0, (void)0, -1);
    PHASEK(1, 1, (void)0, -1);
  }
#undef PHASEK
#undef STGKA
#undef STGKB
#undef REGA
#undef REGB

  #pragma unroll
  for (int fm = 0; fm < 4; ++fm) {
    const int crow = m0 + wr*64 + fm*16 + lhi*4;
    #pragma unroll
    for (int fn = 0; fn < 4; ++fn) {
      const int ccol = n0 + wc*64 + fn*16 + l15;
      #pragma unroll
      for (int j = 0; j < 4; ++j)
        C[(size_t)(crow + j)*N + ccol] = __float2bfloat16(acc[fm][fn][j]);
    }
  }
}

// ---------------- Q-proj (blocks 0-255) + KV-proj (blocks 256-511), one launch
__global__ __launch_bounds__(512, 2) void qkvproj(
    const bf16* __restrict__ xb, const bf16* __restrict__ wqkvb,
    bf16* __restrict__ q0, bf16* __restrict__ kv0)
{
  __shared__ bf16 lds[2*2*2*8192];   // 128 KiB, shared by both branches
  if (blockIdx.x < 256)
    gemm256_body<bf16>(lds, xb, wqkvb, q0, blockIdx.x, 4096, HH, 16);
  else
    gemm128n_body(lds, xb, wqkvb + (size_t)4096*4096, kv0,
                  blockIdx.x - 256, 2048, HH, 8);
}

// ------------------------------------------------------- O-proj (fp32 out)
__global__ __launch_bounds__(512, 2) void oproj(
    const bf16* __restrict__ ao, const bf16* __restrict__ wob,
    float* __restrict__ out)
{
  __shared__ bf16 lds[2*2*2*8192];
  gemm256_body<float>(lds, ao, wob, out, blockIdx.x, HH, HH, 16);
}

// ---------- post: vtrans (blocks 0-1023) + q/k RMSNorm+RoPE (rest), one launch
__global__ __launch_bounds__(256) void postproc(
    const bf16* __restrict__ q0, const bf16* __restrict__ kv0,
    bf16* __restrict__ qr, bf16* __restrict__ kr, bf16* __restrict__ vt,
    const float* __restrict__ cosb, const float* __restrict__ sinb,
    const float* __restrict__ qw_, const float* __restrict__ kw_)
{
  __shared__ bf16 tile[64][65];
  if (blockIdx.x < 1024) {               // vtrans: kv0[m,1024+kv*HD+d] -> vt
    const int idx = blockIdx.x;
    const int bkv = idx & 15, dby = (idx >> 4) & 1, sbx = idx >> 5;
    const int s0 = sbx*64, d0 = dby*64;
    const int bb = bkv >> 3, kv = bkv & 7;
    const int c = threadIdx.x & 63, rbase = threadIdx.x >> 6;
    #pragma unroll
    for (int r = 0; r < 64; r += 4) {
      int sl = r + rbase;
      tile[sl][c] = kv0[(size_t)(bb*SS + s0 + sl)*2048 + 1024 + kv*HD + d0 + c];
    }
    __syncthreads();
    #pragma unroll
    for (int r = 0; r < 64; r += 4) {
      int dl = r + rbase;
      vt[((size_t)bkv*HD + d0 + dl)*SS + s0 + c] = tile[c][dl];
    }
    return;
  }
  const unsigned blk = blockIdx.x - 1024;
  const unsigned QB = (MR*NH)/4;
  const int wid = threadIdx.x >> 6, lane = threadIdx.x & 63;
  const bf16* src; bf16* dst; const float* w; int nh, rowstride; float scale;
  int row;
  if (blk < QB) {
    src = q0; dst = qr; w = qw_; nh = NH; rowstride = 4096;
    scale = 0.08838834764831845f*1.44269504088896341f;
    row = blk*4 + wid;
  } else {
    src = kv0; dst = kr; w = kw_; nh = NKV; rowstride = 2048;
    scale = 1.0f;
    row = (blk - QB)*4 + wid;
  }
  const int m = row / nh, h = row % nh;
  const int b = m / SS, s = m % SS;
  const bf16* sp = src + (size_t)m*rowstride + h*HD;
  float v1 = __bfloat162float(sp[lane]);
  float v2 = __bfloat162float(sp[lane + 64]);
  float ss = v1*v1 + v2*v2;
  #pragma unroll
  for (int msk = 1; msk < 64; msk <<= 1) ss += __shfl_xor(ss, msk);
  float r = rsqrtf(ss*(1.f/128.f) + 1e-6f) * scale;
  float n1 = v1*r*w[lane], n2 = v2*r*w[lane + 64];
  const float* cp  = cosb + (size_t)m*HD;
  const float* sip = sinb + (size_t)m*HD;
  float o1 = n1*cp[lane]      - n2*sip[lane];
  float o2 = n2*cp[lane + 64] + n1*sip[lane + 64];
  bf16* dp = dst + ((size_t)(b*nh + h)*SS + s)*HD;
  dp[lane]      = __float2bfloat16(o1);
  dp[lane + 64] = __float2bfloat16(o2);
}

// ------------------------------------------------ causal GQA flash attention
// 8 waves x 32 q-rows, KVBLK=64, swapped QK^T / swapped PV (lane-local q),
// max3-fusable tree, cvt_pk+permlane32 P re-fragment, defer-max,
// XOR-swizzled K/V via gload_lds, dbuf, LPT dispatch, deferred lrow combine.
// Epilogue: round-17 scalar-write form (cvtpk-packed variant measured
// neutral-to-negative in r18 and cost absmax margin).
__global__ __launch_bounds__(512, 2) void attn_fwd(
    const bf16* __restrict__ qr, const bf16* __restrict__ kr,
    const bf16* __restrict__ vt, bf16* __restrict__ ao)
{
  __shared__ __align__(16) char smem[65536];   // 2 x (16KB K + 16KB V)

  const int L = blockIdx.x;
  const int j = L >> 6;            // 0..7, longest (j=0) dispatched first
  const int bh = L & 63;
  const int b = bh >> 5, h = bh & 31, kvh = h >> 2;

  const int tid = threadIdx.x;
  const int wid = tid >> 6, lane = tid & 63;
  const int l31 = lane & 31, hi = lane >> 5;
  const unsigned hi16 = hi << 4;
  const unsigned swz = (lane & 7) << 4;

  const int qw0 = (wid < 4) ? (j*128 + wid*32) : ((15 - j)*128 + (wid - 4)*32);
  const int NT = 32 - 2*j;
  const int qlane = qw0 + l31;

  const bf16* Qp = qr + ((size_t)(b*NH + h)*SS + qlane)*HD;
  const bf16* Kp = kr + (size_t)(b*NKV + kvh)*SS*HD;
  const bf16* Vp = vt + (size_t)(b*NKV + kvh)*HD*SS;   // [HD][S]

  const int krA = tid >> 4;
  const int ksA = tid & 15;
  const int vrA = tid >> 3;
  const int vsA = tid & 7;
  const int kswz = (ksA ^ (krA & 7))*8;
  const int vswz = (vsA ^ (vrA & 7))*8;

#define STAGE_ATTN(buf, kvbase) do {                                        \
    char* kb = smem + (buf)*32768;                                          \
    char* vb = kb + 16384;                                                  \
    gload16(Kp + (size_t)(krA + (kvbase))*HD + kswz,      kb + tid*16);     \
    gload16(Kp + (size_t)(krA + 32 + (kvbase))*HD + kswz, kb + 8192 + tid*16); \
    gload16(Vp + (size_t)vrA*SS + (kvbase) + vswz,        vb + tid*16);     \
    gload16(Vp + (size_t)(vrA + 64)*SS + (kvbase) + vswz, vb + 8192 + tid*16); \
  } while (0)

  STAGE_ATTN(0, 0);
  bf16x8 qf[8];
  #pragma unroll
  for (int kd = 0; kd < 8; ++kd)
    qf[kd] = *(const bf16x8*)(Qp + kd*16 + hi*8);
  asm volatile("s_waitcnt vmcnt(0)" ::: "memory");
  __builtin_amdgcn_s_barrier();
  CFENCE;

  f32x16 o0, o1, o2, o3;
  #pragma unroll
  for (int r = 0; r < 16; ++r) { o0[r] = 0.f; o1[r] = 0.f; o2[r] = 0.f; o3[r] = 0.f; }
  float mrow = -1e30f, lrow = 0.f;   // lrow is the PER-HALF partial sum

  for (int t = 0; t < NT; ++t) {
    const int p = t & 1;
    const char* KsB = smem + p*32768;
    const char* VsB = KsB + 16384;
    if (t + 1 < NT) STAGE_ATTN(p ^ 1, (t + 1)*64);
    const int kv0 = t*64;

    if (kv0 <= qw0 + 31) {
      f32x16 s0, s1;
      #pragma unroll
      for (int r = 0; r < 16; ++r) { s0[r] = 0.f; s1[r] = 0.f; }
      #pragma unroll
      for (int kd = 0; kd < 8; ++kd) {
        bf16x8 k0f = *(const bf16x8*)(KsB + l31*256        + (((unsigned)(kd*32) + hi16) ^ swz));
        bf16x8 k1f = *(const bf16x8*)(KsB + (32 + l31)*256 + (((unsigned)(kd*32) + hi16) ^ swz));
        s0 = mfma32(k0f, qf[kd], s0);
        s1 = mfma32(k1f, qf[kd], s1);
      }
      if (kv0 + 63 > qw0) {
        #pragma unroll
        for (int r = 0; r < 16; ++r) {
          const int off = (r & 3) + 8*(r >> 2) + 4*hi;
          if (kv0 + off > qlane)      s0[r] = -1e30f;
          if (kv0 + 32 + off > qlane) s1[r] = -1e30f;
        }
      }
      // ILP-wide max tree (max3-fusable)
      float mg[8];
      #pragma unroll
      for (int r = 0; r < 8; ++r)
        mg[r] = fmaxf(fmaxf(s0[r], s0[r + 8]), fmaxf(s1[r], s1[r + 8]));
      float ta = fmaxf(fmaxf(mg[0], mg[1]), mg[2]);
      float tb = fmaxf(fmaxf(mg[3], mg[4]), mg[5]);
      float tmax = fmaxf(fmaxf(ta, tb), fmaxf(mg[6], mg[7]));
      tmax = fmaxf(tmax, __shfl_xor(tmax, 32));      // mrow sync across halves
      if (!__all(tmax <= mrow + 8.f)) {      // T13 defer-max (log2 domain)
        float mnew = fmaxf(mrow, tmax);
        float alpha = fexp2(mrow - mnew);    // identical in both halves
        mrow = mnew;
        lrow *= alpha;
        #pragma unroll
        for (int r = 0; r < 16; ++r) {
          o0[r] *= alpha; o1[r] *= alpha; o2[r] *= alpha; o3[r] *= alpha;
        }
      }
      float tsum = 0.f;
      #pragma unroll
      for (int r = 0; r < 16; ++r) { s0[r] = fexp2(s0[r] - mrow); tsum += s0[r]; }
      #pragma unroll
      for (int r = 0; r < 16; ++r) { s1[r] = fexp2(s1[r] - mrow); tsum += s1[r]; }
      lrow += tsum;                          // partial; combined after loop

      #pragma unroll
      for (int ks = 0; ks < 4; ++ks) {
        const int bb0 = (ks & 1)*8;
        float p0,p1,p2,p3,p4,p5,p6,p7;
        if (ks < 2) { p0=s0[bb0+0];p1=s0[bb0+1];p2=s0[bb0+2];p3=s0[bb0+3];
                      p4=s0[bb0+4];p5=s0[bb0+5];p6=s0[bb0+6];p7=s0[bb0+7]; }
        else        { p0=s1[bb0+0];p1=s1[bb0+1];p2=s1[bb0+2];p3=s1[bb0+3];
                      p4=s1[bb0+4];p5=s1[bb0+5];p6=s1[bb0+6];p7=s1[bb0+7]; }
        unsigned c01 = cvtpk(p0,p1), c23 = cvtpk(p2,p3);
        unsigned c45 = cvtpk(p4,p5), c67 = cvtpk(p6,p7);
        unsigned w0 = c01, w2 = c45; swap32(w0, w2);
        unsigned w1 = c23, w3 = c67; swap32(w1, w3);
        union { unsigned u[4]; bf16x8 v; } pa;
        pa.u[0]=w0; pa.u[1]=w1; pa.u[2]=w2; pa.u[3]=w3;
        #pragma unroll
        for (int dt = 0; dt < 4; ++dt) {
          bf16x8 vf = *(const bf16x8*)(VsB + (dt*32 + l31)*128 +
                                       (((unsigned)(ks*32) + hi16) ^ swz));
          f32x16 &oo = (dt==0)?o0:(dt==1)?o1:(dt==2)?o2:o3;
          oo = mfma32(vf, pa.v, oo);
        }
      }
    }

    asm volatile("s_waitcnt vmcnt(0)" ::: "memory");
    __builtin_amdgcn_s_barrier();
    CFENCE;
  }
#undef STAGE_ATTN

  lrow += __shfl_xor(lrow, 32);            // single cross-half combine

  // epilogue: transpose O via wave-private LDS, coalesced 16B stores
  const float invl = 1.f / lrow;
  char* ow = smem + wid*4096;
  bf16* aop = ao + ((size_t)b*SS + qlane)*HH + h*HD;
  const unsigned eswz = (l31 & 7) << 4;
  #pragma unroll
  for (int half = 0; half < 2; ++half) {
    #pragma unroll
    for (int hh = 0; hh < 2; ++hh) {
      #pragma unroll
      for (int r = 0; r < 16; ++r) {
        const int dcol = hh*32 + (r & 3) + 8*(r >> 2) + 4*hi;
        float val = ((half*2+hh)==0 ? o0[r] : (half*2+hh)==1 ? o1[r]
                     : (half*2+hh)==2 ? o2[r] : o3[r]) * invl;
        *(bf16*)(ow + l31*128 + (((unsigned)(dcol*2)) ^ eswz)) = __float2bfloat16(val);
      }
    }
    #pragma unroll
    for (int m = 0; m < 4; ++m) {
      const int c0 = hi*32 + m*8;
      bf16x8 vv = *(const bf16x8*)(ow + l31*128 + (((unsigned)(c0*2)) ^ eswz));
      *(bf16x8*)(aop + half*64 + c0) = vv;
    }
  }
}

// --------------------------------------------------------------------- launch
extern "C" void kernel_launch(void* const* d_in, const int* in_sizes, int n_in,
                              void* d_out, int out_size, void* d_ws, size_t ws_size,
                              hipStream_t stream)
{
  const float* x    = (const float*)d_in[0];
  const float* cosb = (const float*)d_in[1];
  const float* sinb = (const float*)d_in[2];
  const float* wq   = (const float*)d_in[3];
  const float* wk   = (const float*)d_in[4];
  const float* wv   = (const float*)d_in[5];
  const float* wo   = (const float*)d_in[6];
  const float* qnw  = (const float*)d_in[7];
  const float* knw  = (const float*)d_in[8];
  float* out = (float*)d_out;

  char* ws = (char*)d_ws;
  bf16* xb    = (bf16*)(ws);                  // 32 MiB
  bf16* wqkvb = (bf16*)(ws +  33554432);      // 48 MiB [6144][4096] Wq|Wk|Wv
  bf16* wob   = (bf16*)(ws +  83886080);      // 32 MiB
  bf16* q0    = (bf16*)(ws + 117440512);      // 32 MiB [4096][4096]
  bf16* kv0   = (bf16*)(ws + 150994944);      // 16 MiB [4096][2048] K|V
  bf16* qr    = (bf16*)(ws + 167772160);      // 32 MiB (end 192 MiB)
  // ordering-safe aliases:
  bf16* vt = xb;                              // xb dead after projections
  bf16* kr = (bf16*)(ws + 8388608);           // xb+8MiB, same lifetime
  bf16* ao = q0;                              // q0 dead after q normrope

  f2b5<<<2100, 256, 0, stream>>>(x, wq, wk, wv, wo,
                                 xb, wqkvb,
                                 wqkvb + (size_t)4096*4096,
                                 wqkvb + (size_t)5120*4096,
                                 wob);

  // fused Q-proj (256 blocks) + KV-proj (256 blocks), Q first (LPT)
  qkvproj<<<512, 512, 0, stream>>>(xb, wqkvb, q0, kv0);

  // fused vtrans + q/k RMSNorm+RoPE (q scale folds 1/sqrt(HD)*log2(e))
  postproc<<<1024 + (MR*NH)/4 + (MR*NKV)/4, 256, 0, stream>>>(
      q0, kv0, qr, kr, vt, cosb, sinb, qnw, knw);

  attn_fwd<<<512, 512, 0, stream>>>(qr, kr, vt, ao);

  oproj<<<256, 512, 0, stream>>>(ao, wob, out);
}

// Round 22
// 489.637 us; speedup vs baseline: 1.0123x; 1.0123x over previous
//
#include <hip/hip_runtime.h>
#include <hip/hip_bf16.h>

#define NB  2
#define SS  2048
#define HH  4096
#define NH  32
#define NKV 8
#define HD  128
#define MR  (NB*SS)   // 4096 token rows

typedef __bf16 bf16x8 __attribute__((ext_vector_type(8)));
typedef float  f32x4  __attribute__((ext_vector_type(4)));
typedef float  f32x16 __attribute__((ext_vector_type(16)));
using bf16 = __hip_bfloat16;

__device__ __forceinline__ f32x4 mfma16(bf16x8 a, bf16x8 b, f32x4 c) {
  return __builtin_amdgcn_mfma_f32_16x16x32_bf16(a, b, c, 0, 0, 0);
}
__device__ __forceinline__ f32x16 mfma32(bf16x8 a, bf16x8 b, f32x16 c) {
  return __builtin_amdgcn_mfma_f32_32x32x16_bf16(a, b, c, 0, 0, 0);
}
__device__ __forceinline__ unsigned cvtpk(float lo, float hi) {
  unsigned r; asm("v_cvt_pk_bf16_f32 %0, %1, %2" : "=v"(r) : "v"(lo), "v"(hi));
  return r;
}
// Used ONLY with two genuinely-distinct producer values (cvtpk results,
// >=2 instrs apart). Round 10/11 lesson: no self-copy reduces.
__device__ __forceinline__ void swap32(unsigned &a, unsigned &b) {
  asm volatile("v_permlane32_swap_b32 %0, %1" : "+v"(a), "+v"(b));
}
__device__ __forceinline__ float fexp2(float x) {
  float r; asm("v_exp_f32 %0, %1" : "=v"(r) : "v"(x)); return r;
}

typedef const __attribute__((address_space(1))) void gv_t;
typedef __attribute__((address_space(3))) void lv_t;
__device__ __forceinline__ void gload16(const void* g, void* l) {
  __builtin_amdgcn_global_load_lds((gv_t*)g, (lv_t*)l, 16, 0, 0);
}
#define CFENCE asm volatile("" ::: "memory")

// --------------------------------- fp32 -> bf16, 5 segments in one launch
__global__ void f2b5(const float* __restrict__ s0, const float* __restrict__ s1,
                     const float* __restrict__ s2, const float* __restrict__ s3,
                     const float* __restrict__ s4,
                     bf16* __restrict__ d0, bf16* __restrict__ d1,
                     bf16* __restrict__ d2, bf16* __restrict__ d3,
                     bf16* __restrict__ d4)
{
  const unsigned c0 = 4194304u, c1 = 8388608u, c2 = 9437184u, c3 = 10485760u,
                 c4 = 14680064u;
  unsigned i = blockIdx.x*blockDim.x + threadIdx.x;
  unsigned stride = gridDim.x*blockDim.x;
  for (unsigned u = i; u < c4; u += stride) {
    const float* s; bf16* d; unsigned off;
    if (u < c0)      { s = s0; d = d0; off = u; }
    else if (u < c1) { s = s1; d = d1; off = u - c0; }
    else if (u < c2) { s = s2; d = d2; off = u - c1; }
    else if (u < c3) { s = s3; d = d3; off = u - c2; }
    else             { s = s4; d = d4; off = u - c3; }
    float4 v = *(const float4*)(s + (size_t)off*4);
    __hip_bfloat16 b0 = __float2bfloat16(v.x);
    __hip_bfloat16 b1 = __float2bfloat16(v.y);
    __hip_bfloat16 b2 = __float2bfloat16(v.z);
    __hip_bfloat16 b3 = __float2bfloat16(v.w);
    ushort4 o;
    o.x = *reinterpret_cast<unsigned short*>(&b0);
    o.y = *reinterpret_cast<unsigned short*>(&b1);
    o.z = *reinterpret_cast<unsigned short*>(&b2);
    o.w = *reinterpret_cast<unsigned short*>(&b3);
    *(ushort4*)((unsigned short*)d + (size_t)off*4) = o;
  }
}

// ------------------------------------------------- C[M,N] = A[M,K] @ Bt[N,K]^T
// Round-14 measured-best body (45.5-47% MfmaUtil, 0 conflicts). Staging
// discipline: every staged unit's LAST READ completes before a barrier that
// precedes the stage (audited p1..p8 -- no same-phase read/write hazard).
template<typename OutT>
__device__ __forceinline__ void gemm256_body(
    bf16* lds, const bf16* __restrict__ A, const bf16* __restrict__ Bt,
    OutT* __restrict__ C, int bid, int N, int K, int tilesX)
{
  const int cpx = 32;                      // 256 tiles / 8 XCDs
  const int wg  = (bid & 7)*cpx + (bid >> 3);
  const int m0 = (wg / tilesX) * 256, n0 = (wg % tilesX) * 256;

  const int tid = threadIdx.x;
  const int l = tid & 63;
  const int l15 = l & 15, lhi = l >> 4;
  const int wid = tid >> 6;
  const int wr = wid >> 2, wc = wid & 3;   // wave tile 128x64

  const int srow = tid >> 2;
  const int sps  = tid & 3;
  const int sls  = (sps - (srow >> 1)) & 3;
  const bf16* ga0 = A  + (size_t)(m0 + srow)*K       + sls*8;
  const bf16* ga1 = A  + (size_t)(m0 + srow + 128)*K + sls*8;
  const bf16* gb0 = Bt + (size_t)(n0 + srow)*K       + sls*8;
  const bf16* gb1 = Bt + (size_t)(n0 + srow + 128)*K + sls*8;
  const int ldst = tid*8;

#define REG(buf, mat, ks) (&lds[(((buf)*2 + (mat))*2 + (ks))*8192])
#define STG_A(buf, ks, kofs) do {                                 \
    gload16(ga0 + (kofs), REG(buf,0,ks) + ldst);                  \
    gload16(ga1 + (kofs), REG(buf,0,ks) + ldst + 4096);           \
  } while (0)
#define STG_B(buf, ks, kofs) do {                                 \
    gload16(gb0 + (kofs), REG(buf,1,ks) + ldst);                  \
    gload16(gb1 + (kofs), REG(buf,1,ks) + ldst + 4096);           \
  } while (0)

  f32x4 acc[8][4];
  #pragma unroll
  for (int fm = 0; fm < 8; ++fm)
    #pragma unroll
    for (int fn = 0; fn < 4; ++fn)
      #pragma unroll
      for (int e = 0; e < 4; ++e) acc[fm][fn][e] = 0.f;

  const int arow = wr*128 + l15;
  const int brow = wc*64  + l15;
  const int psl  = (lhi + (l15 >> 1)) & 3;

  bf16x8 bv[4];

#define PHASE(PB, KS, FMH, RB, STG, WN) do {                               \
    const bf16* Ar_ = REG(PB, 0, KS);                                      \
    const bf16* Br_ = REG(PB, 1, KS);                                      \
    bf16x8 af[4];                                                          \
    for (int fm = 0; fm < 4; ++fm)                                         \
      af[fm] = *(const bf16x8*)(Ar_ + (arow + (FMH)*64 + fm*16)*32 + psl*8); \
    if (RB) {                                                              \
      for (int fn = 0; fn < 4; ++fn)                                       \
        bv[fn] = *(const bf16x8*)(Br_ + (brow + fn*16)*32 + psl*8);        \
    }                                                                      \
    STG;                                                                   \
    CFENCE;                                                                \
    __builtin_amdgcn_s_barrier();                                          \
    __builtin_amdgcn_s_setprio(1);                                         \
    for (int fm = 0; fm < 4; ++fm)                                         \
      for (int fn = 0; fn < 4; ++fn)                                       \
        acc[(FMH)*4 + fm][fn] = mfma16(af[fm], bv[fn], acc[(FMH)*4 + fm][fn]); \
    __builtin_amdgcn_s_setprio(0);                                         \
    if ((WN) == 6)      asm volatile("s_waitcnt vmcnt(6)" ::: "memory");   \
    else if ((WN) == 0) asm volatile("s_waitcnt vmcnt(0)" ::: "memory");   \
    __builtin_amdgcn_s_barrier();                                          \
    CFENCE;                                                                \
  } while (0)

  const int nt = K >> 6;

  STG_A(0, 0, 0);  STG_B(0, 0, 0);  STG_A(0, 1, 32);  STG_B(0, 1, 32);
  STG_A(1, 0, 64); STG_B(1, 0, 64); STG_B(1, 1, 96);
  asm volatile("s_waitcnt vmcnt(6)" ::: "memory");
  __builtin_amdgcn_s_barrier();
  CFENCE;

  for (int i = 0; i < (nt >> 1) - 1; ++i) {
    const int t  = i << 1;
    const int k1 = ((t + 1) << 6) + 32;
    const int k2 = (t + 2) << 6;
    const int k3 = (t + 3) << 6;
    PHASE(0, 0, 0, true,  STG_A(1, 1, k1),      -1);
    PHASE(0, 0, 1, false, STG_B(0, 0, k2),      -1);
    PHASE(0, 1, 0, true,  STG_A(0, 0, k2),      -1);
    PHASE(0, 1, 1, false, STG_B(0, 1, k2 + 32),  6);
    PHASE(1, 0, 0, true,  STG_A(0, 1, k2 + 32), -1);
    PHASE(1, 0, 1, false, STG_B(1, 0, k3),      -1);
    PHASE(1, 1, 0, true,  STG_A(1, 0, k3),      -1);
    PHASE(1, 1, 1, false, STG_B(1, 1, k3 + 32),  6);
  }
  {
    const int k1 = ((nt - 1) << 6) + 32;
    PHASE(0, 0, 0, true,  STG_A(1, 1, k1), -1);
    PHASE(0, 0, 1, false, (void)0,         -1);
    PHASE(0, 1, 0, true,  (void)0,         -1);
    PHASE(0, 1, 1, false, (void)0,          0);
    PHASE(1, 0, 0, true,  (void)0,         -1);
    PHASE(1, 0, 1, false, (void)0,         -1);
    PHASE(1, 1, 0, true,  (void)0,         -1);
    PHASE(1, 1, 1, false, (void)0,         -1);
  }
#undef PHASE
#undef STG_A
#undef STG_B
#undef REG

  #pragma unroll
  for (int fm = 0; fm < 8; ++fm) {
    const int crow = m0 + wr*128 + fm*16 + lhi*4;
    #pragma unroll
    for (int fn = 0; fn < 4; ++fn) {
      const int ccol = n0 + wc*64 + fn*16 + l15;
      #pragma unroll
      for (int j = 0; j < 4; ++j) {
        if constexpr (sizeof(OutT) == 2)
          C[(size_t)(crow + j)*N + ccol] = __float2bfloat16(acc[fm][fn][j]);
        else
          C[(size_t)(crow + j)*N + ccol] = acc[fm][fn][j];
      }
    }
  }
}

// ------------------------------------------------- 128x256-tile GEMM body
// (KV-proj.) RACE FIX (r22): the old schedule staged unit (buf,ks) in the
// SAME phase that read it -- a neighbor wave's in-flight ds_reads could be
// overwritten by the gload_lds data-return (no barrier between). Latent
// rounds 9-19; manifested r20/r21 (nondeterministic post-replay absmax).
// New rotation (gemm256 discipline): p1 reads(0,ks0) stages (1,ks1)<-t+1;
// p2 reads(0,ks1) stages (0,ks0)<-t+2; p3 reads(1,ks0) stages (0,ks1);
// p4 reads(1,ks1) stages (1,ks0)<-t+3. Every staged unit's last read is
// separated from the stage by a full barrier. Ledger: 3 loads/stage,
// uniform vmcnt(6) (lands exactly the next phase's unit); drain 6->3->0.
__device__ __forceinline__ void gemm128n_body(
    bf16* lds, const bf16* __restrict__ A, const bf16* __restrict__ Bt,
    bf16* __restrict__ C, int bid, int N, int K, int tilesX)
{
  const int cpx = 32;
  const int wg  = (bid & 7)*cpx + (bid >> 3);
  const int m0 = (wg / tilesX) * 128, n0 = (wg % tilesX) * 256;

  const int tid = threadIdx.x;
  const int l = tid & 63;
  const int l15 = l & 15, lhi = l >> 4;
  const int wid = tid >> 6;
  const int wr = wid >> 2, wc = wid & 3;   // wave tile 64x64

  const int srow = tid >> 2;
  const int sps  = tid & 3;
  const int sls  = (sps - (srow >> 1)) & 3;
  const bf16* gaA = A  + (size_t)(m0 + srow)*K       + sls*8;
  const bf16* gb0 = Bt + (size_t)(n0 + srow)*K       + sls*8;
  const bf16* gb1 = Bt + (size_t)(n0 + srow + 128)*K + sls*8;
  const int ldst = tid*8;

#define REGA(buf, ks) (&lds[((buf)*2 + (ks))*12288])
#define REGB(buf, ks) (&lds[((buf)*2 + (ks))*12288 + 4096])
#define STGKA(buf, ks, kofs) gload16(gaA + (kofs), REGA(buf,ks) + ldst)
#define STGKB(buf, ks, kofs) do {                                 \
    gload16(gb0 + (kofs), REGB(buf,ks) + ldst);                   \
    gload16(gb1 + (kofs), REGB(buf,ks) + ldst + 4096);            \
  } while (0)

  f32x4 acc[4][4];
  #pragma unroll
  for (int fm = 0; fm < 4; ++fm)
    #pragma unroll
    for (int fn = 0; fn < 4; ++fn)
      #pragma unroll
      for (int e = 0; e < 4; ++e) acc[fm][fn][e] = 0.f;

  const int arow = wr*64 + l15;
  const int brow = wc*64 + l15;
  const int psl  = (lhi + (l15 >> 1)) & 3;

#define PHASEK(PB, KS, STG, WN) do {                                       \
    const bf16* Ar_ = REGA(PB, KS);                                        \
    const bf16* Br_ = REGB(PB, KS);                                        \
    bf16x8 af[4], bv[4];                                                   \
    for (int fm = 0; fm < 4; ++fm)                                         \
      af[fm] = *(const bf16x8*)(Ar_ + (arow + fm*16)*32 + psl*8);          \
    for (int fn = 0; fn < 4; ++fn)                                         \
      bv[fn] = *(const bf16x8*)(Br_ + (brow + fn*16)*32 + psl*8);          \
    STG;                                                                   \
    CFENCE;                                                                \
    __builtin_amdgcn_s_barrier();                                          \
    __builtin_amdgcn_s_setprio(1);                                         \
    for (int fm = 0; fm < 4; ++fm)                                         \
      for (int fn = 0; fn < 4; ++fn)                                       \
        acc[fm][fn] = mfma16(af[fm], bv[fn], acc[fm][fn]);                 \
    __builtin_amdgcn_s_setprio(0);                                         \
    if ((WN) == 6)      asm volatile("s_waitcnt vmcnt(6)" ::: "memory");   \
    else if ((WN) == 3) asm volatile("s_waitcnt vmcnt(3)" ::: "memory");   \
    else if ((WN) == 0) asm volatile("s_waitcnt vmcnt(0)" ::: "memory");   \
    __builtin_amdgcn_s_barrier();                                          \
    CFENCE;                                                                \
  } while (0)

  const int nt = K >> 6;

  // prologue: (0,ks0), (0,ks1), (1,ks0) = 9 loads; (1,ks1) staged at p1.
  // vmcnt(6) -> oldest 3 = (0,ks0) landed.
  STGKB(0, 0, 0);  STGKA(0, 0, 0);
  STGKB(0, 1, 32); STGKA(0, 1, 32);
  STGKB(1, 0, 64); STGKA(1, 0, 64);
  asm volatile("s_waitcnt vmcnt(6)" ::: "memory");
  __builtin_amdgcn_s_barrier();
  CFENCE;

  for (int i = 0; i < (nt >> 1) - 1; ++i) {
    const int t  = i << 1;
    const int k1 = ((t + 1) << 6) + 32;      // (1,ks1) <- tile t+1
    const int k2 = (t + 2) << 6;
    const int k3 = (t + 3) << 6;
    PHASEK(0, 0, { STGKB(1, 1, k1);      STGKA(1, 1, k1);      }, 6);
    PHASEK(0, 1, { STGKB(0, 0, k2);      STGKA(0, 0, k2);      }, 6);
    PHASEK(1, 0, { STGKB(0, 1, k2 + 32); STGKA(0, 1, k2 + 32); }, 6);
    PHASEK(1, 1, { STGKB(1, 0, k3);      STGKA(1, 0, k3);      }, 6);
  }
  {  // final iteration (t = nt-2): only (1,ks1) <- tile nt-1 still needed
    const int k1 = ((nt - 1) << 6) + 32;
    PHASEK(0, 0, { STGKB(1, 1, k1); STGKA(1, 1, k1); }, 6);
    PHASEK(0, 1, (void)0, 3);
    PHASEK(1, 0, (void)0, 0);
    PHASEK(1, 1, (void)0, -1);
  }
#undef PHASEK
#undef STGKA
#undef STGKB
#undef REGA
#undef REGB

  #pragma unroll
  for (int fm = 0; fm < 4; ++fm) {
    const int crow = m0 + wr*64 + fm*16 + lhi*4;
    #pragma unroll
    for (int fn = 0; fn < 4; ++fn) {
      const int ccol = n0 + wc*64 + fn*16 + l15;
      #pragma unroll
      for (int j = 0; j < 4; ++j)
        C[(size_t)(crow + j)*N + ccol] = __float2bfloat16(acc[fm][fn][j]);
    }
  }
}

// ---------------- Q-proj (blocks 0-255) + KV-proj (blocks 256-511), one launch
__global__ __launch_bounds__(512, 2) void qkvproj(
    const bf16* __restrict__ xb, const bf16* __restrict__ wqkvb,
    bf16* __restrict__ q0, bf16* __restrict__ kv0)
{
  __shared__ bf16 lds[2*2*2*8192];   // 128 KiB, shared by both branches
  if (blockIdx.x < 256)
    gemm256_body<bf16>(lds, xb, wqkvb, q0, blockIdx.x, 4096, HH, 16);
  else
    gemm128n_body(lds, xb, wqkvb + (size_t)4096*4096, kv0,
                  blockIdx.x - 256, 2048, HH, 8);
}

// ------------------------------------------------------- O-proj (fp32 out)
__global__ __launch_bounds__(512, 2) void oproj(
    const bf16* __restrict__ ao, const bf16* __restrict__ wob,
    float* __restrict__ out)
{
  __shared__ bf16 lds[2*2*2*8192];
  gemm256_body<float>(lds, ao, wob, out, blockIdx.x, HH, HH, 16);
}

// ---------- post: vtrans (blocks 0-1023) + q/k RMSNorm+RoPE (rest), one launch
__global__ __launch_bounds__(256) void postproc(
    const bf16* __restrict__ q0, const bf16* __restrict__ kv0,
    bf16* __restrict__ qr, bf16* __restrict__ kr, bf16* __restrict__ vt,
    const float* __restrict__ cosb, const float* __restrict__ sinb,
    const float* __restrict__ qw_, const float* __restrict__ kw_)
{
  __shared__ bf16 tile[64][65];
  if (blockIdx.x < 1024) {               // vtrans: kv0[m,1024+kv*HD+d] -> vt
    const int idx = blockIdx.x;
    const int bkv = idx & 15, dby = (idx >> 4) & 1, sbx = idx >> 5;
    const int s0 = sbx*64, d0 = dby*64;
    const int bb = bkv >> 3, kv = bkv & 7;
    const int c = threadIdx.x & 63, rbase = threadIdx.x >> 6;
    #pragma unroll
    for (int r = 0; r < 64; r += 4) {
      int sl = r + rbase;
      tile[sl][c] = kv0[(size_t)(bb*SS + s0 + sl)*2048 + 1024 + kv*HD + d0 + c];
    }
    __syncthreads();
    #pragma unroll
    for (int r = 0; r < 64; r += 4) {
      int dl = r + rbase;
      vt[((size_t)bkv*HD + d0 + dl)*SS + s0 + c] = tile[c][dl];
    }
    return;
  }
  const unsigned blk = blockIdx.x - 1024;
  const unsigned QB = (MR*NH)/4;
  const int wid = threadIdx.x >> 6, lane = threadIdx.x & 63;
  const bf16* src; bf16* dst; const float* w; int nh, rowstride; float scale;
  int row;
  if (blk < QB) {
    src = q0; dst = qr; w = qw_; nh = NH; rowstride = 4096;
    scale = 0.08838834764831845f*1.44269504088896341f;
    row = blk*4 + wid;
  } else {
    src = kv0; dst = kr; w = kw_; nh = NKV; rowstride = 2048;
    scale = 1.0f;
    row = (blk - QB)*4 + wid;
  }
  const int m = row / nh, h = row % nh;
  const int b = m / SS, s = m % SS;
  const bf16* sp = src + (size_t)m*rowstride + h*HD;
  float v1 = __bfloat162float(sp[lane]);
  float v2 = __bfloat162float(sp[lane + 64]);
  float ss = v1*v1 + v2*v2;
  #pragma unroll
  for (int msk = 1; msk < 64; msk <<= 1) ss += __shfl_xor(ss, msk);
  float r = rsqrtf(ss*(1.f/128.f) + 1e-6f) * scale;
  float n1 = v1*r*w[lane], n2 = v2*r*w[lane + 64];
  const float* cp  = cosb + (size_t)m*HD;
  const float* sip = sinb + (size_t)m*HD;
  float o1 = n1*cp[lane]      - n2*sip[lane];
  float o2 = n2*cp[lane + 64] + n1*sip[lane + 64];
  bf16* dp = dst + ((size_t)(b*nh + h)*SS + s)*HD;
  dp[lane]      = __float2bfloat16(o1);
  dp[lane + 64] = __float2bfloat16(o2);
}

// ------------------------------------------------ causal GQA flash attention
// 8 waves x 32 q-rows, KVBLK=64, swapped QK^T / swapped PV (lane-local q),
// max3-fusable tree, cvt_pk+permlane32 P re-fragment, defer-max,
// XOR-swizzled K/V via gload_lds, dbuf, LPT dispatch, deferred lrow combine.
// STAGE safety: buffer p^1 staged at iter t was last read at iter t-1, whose
// closing vmcnt(0)+barrier completes after all reads -- no WAR hazard.
__global__ __launch_bounds__(512, 2) void attn_fwd(
    const bf16* __restrict__ qr, const bf16* __restrict__ kr,
    const bf16* __restrict__ vt, bf16* __restrict__ ao)
{
  __shared__ __align__(16) char smem[65536];   // 2 x (16KB K + 16KB V)

  const int L = blockIdx.x;
  const int j = L >> 6;            // 0..7, longest (j=0) dispatched first
  const int bh = L & 63;
  const int b = bh >> 5, h = bh & 31, kvh = h >> 2;

  const int tid = threadIdx.x;
  const int wid = tid >> 6, lane = tid & 63;
  const int l31 = lane & 31, hi = lane >> 5;
  const unsigned hi16 = hi << 4;
  const unsigned swz = (lane & 7) << 4;

  const int qw0 = (wid < 4) ? (j*128 + wid*32) : ((15 - j)*128 + (wid - 4)*32);
  const int NT = 32 - 2*j;
  const int qlane = qw0 + l31;

  const bf16* Qp = qr + ((size_t)(b*NH + h)*SS + qlane)*HD;
  const bf16* Kp = kr + (size_t)(b*NKV + kvh)*SS*HD;
  const bf16* Vp = vt + (size_t)(b*NKV + kvh)*HD*SS;   // [HD][S]

  const int krA = tid >> 4;
  const int ksA = tid & 15;
  const int vrA = tid >> 3;
  const int vsA = tid & 7;
  const int kswz = (ksA ^ (krA & 7))*8;
  const int vswz = (vsA ^ (vrA & 7))*8;

#define STAGE_ATTN(buf, kvbase) do {                                        \
    char* kb = smem + (buf)*32768;                                          \
    char* vb = kb + 16384;                                                  \
    gload16(Kp + (size_t)(krA + (kvbase))*HD + kswz,      kb + tid*16);     \
    gload16(Kp + (size_t)(krA + 32 + (kvbase))*HD + kswz, kb + 8192 + tid*16); \
    gload16(Vp + (size_t)vrA*SS + (kvbase) + vswz,        vb + tid*16);     \
    gload16(Vp + (size_t)(vrA + 64)*SS + (kvbase) + vswz, vb + 8192 + tid*16); \
  } while (0)

  STAGE_ATTN(0, 0);
  bf16x8 qf[8];
  #pragma unroll
  for (int kd = 0; kd < 8; ++kd)
    qf[kd] = *(const bf16x8*)(Qp + kd*16 + hi*8);
  asm volatile("s_waitcnt vmcnt(0)" ::: "memory");
  __builtin_amdgcn_s_barrier();
  CFENCE;

  f32x16 o0, o1, o2, o3;
  #pragma unroll
  for (int r = 0; r < 16; ++r) { o0[r] = 0.f; o1[r] = 0.f; o2[r] = 0.f; o3[r] = 0.f; }
  float mrow = -1e30f, lrow = 0.f;   // lrow is the PER-HALF partial sum

  for (int t = 0; t < NT; ++t) {
    const int p = t & 1;
    const char* KsB = smem + p*32768;
    const char* VsB = KsB + 16384;
    if (t + 1 < NT) STAGE_ATTN(p ^ 1, (t + 1)*64);
    const int kv0 = t*64;

    if (kv0 <= qw0 + 31) {
      f32x16 s0, s1;
      #pragma unroll
      for (int r = 0; r < 16; ++r) { s0[r] = 0.f; s1[r] = 0.f; }
      #pragma unroll
      for (int kd = 0; kd < 8; ++kd) {
        bf16x8 k0f = *(const bf16x8*)(KsB + l31*256        + (((unsigned)(kd*32) + hi16) ^ swz));
        bf16x8 k1f = *(const bf16x8*)(KsB + (32 + l31)*256 + (((unsigned)(kd*32) + hi16) ^ swz));
        s0 = mfma32(k0f, qf[kd], s0);
        s1 = mfma32(k1f, qf[kd], s1);
      }
      if (kv0 + 63 > qw0) {
        #pragma unroll
        for (int r = 0; r < 16; ++r) {
          const int off = (r & 3) + 8*(r >> 2) + 4*hi;
          if (kv0 + off > qlane)      s0[r] = -1e30f;
          if (kv0 + 32 + off > qlane) s1[r] = -1e30f;
        }
      }
      // ILP-wide max tree (max3-fusable)
      float mg[8];
      #pragma unroll
      for (int r = 0; r < 8; ++r)
        mg[r] = fmaxf(fmaxf(s0[r], s0[r + 8]), fmaxf(s1[r], s1[r + 8]));
      float ta = fmaxf(fmaxf(mg[0], mg[1]), mg[2]);
      float tb = fmaxf(fmaxf(mg[3], mg[4]), mg[5]);
      float tmax = fmaxf(fmaxf(ta, tb), fmaxf(mg[6], mg[7]));
      tmax = fmaxf(tmax, __shfl_xor(tmax, 32));      // mrow sync across halves
      if (!__all(tmax <= mrow + 8.f)) {      // T13 defer-max (log2 domain)
        float mnew = fmaxf(mrow, tmax);
        float alpha = fexp2(mrow - mnew);    // identical in both halves
        mrow = mnew;
        lrow *= alpha;
        #pragma unroll
        for (int r = 0; r < 16; ++r) {
          o0[r] *= alpha; o1[r] *= alpha; o2[r] *= alpha; o3[r] *= alpha;
        }
      }
      float tsum = 0.f;
      #pragma unroll
      for (int r = 0; r < 16; ++r) { s0[r] = fexp2(s0[r] - mrow); tsum += s0[r]; }
      #pragma unroll
      for (int r = 0; r < 16; ++r) { s1[r] = fexp2(s1[r] - mrow); tsum += s1[r]; }
      lrow += tsum;                          // partial; combined after loop

      #pragma unroll
      for (int ks = 0; ks < 4; ++ks) {
        const int bb0 = (ks & 1)*8;
        float p0,p1,p2,p3,p4,p5,p6,p7;
        if (ks < 2) { p0=s0[bb0+0];p1=s0[bb0+1];p2=s0[bb0+2];p3=s0[bb0+3];
                      p4=s0[bb0+4];p5=s0[bb0+5];p6=s0[bb0+6];p7=s0[bb0+7]; }
        else        { p0=s1[bb0+0];p1=s1[bb0+1];p2=s1[bb0+2];p3=s1[bb0+3];
                      p4=s1[bb0+4];p5=s1[bb0+5];p6=s1[bb0+6];p7=s1[bb0+7]; }
        unsigned c01 = cvtpk(p0,p1), c23 = cvtpk(p2,p3);
        unsigned c45 = cvtpk(p4,p5), c67 = cvtpk(p6,p7);
        unsigned w0 = c01, w2 = c45; swap32(w0, w2);
        unsigned w1 = c23, w3 = c67; swap32(w1, w3);
        union { unsigned u[4]; bf16x8 v; } pa;
        pa.u[0]=w0; pa.u[1]=w1; pa.u[2]=w2; pa.u[3]=w3;
        #pragma unroll
        for (int dt = 0; dt < 4; ++dt) {
          bf16x8 vf = *(const bf16x8*)(VsB + (dt*32 + l31)*128 +
                                       (((unsigned)(ks*32) + hi16) ^ swz));
          f32x16 &oo = (dt==0)?o0:(dt==1)?o1:(dt==2)?o2:o3;
          oo = mfma32(vf, pa.v, oo);
        }
      }
    }

    asm volatile("s_waitcnt vmcnt(0)" ::: "memory");
    __builtin_amdgcn_s_barrier();
    CFENCE;
  }
#undef STAGE_ATTN

  lrow += __shfl_xor(lrow, 32);            // single cross-half combine

  // epilogue: transpose O via wave-private LDS, coalesced 16B stores
  const float invl = 1.f / lrow;
  char* ow = smem + wid*4096;
  bf16* aop = ao + ((size_t)b*SS + qlane)*HH + h*HD;
  const unsigned eswz = (l31 & 7) << 4;
  #pragma unroll
  for (int half = 0; half < 2; ++half) {
    #pragma unroll
    for (int hh = 0; hh < 2; ++hh) {
      #pragma unroll
      for (int r = 0; r < 16; ++r) {
        const int dcol = hh*32 + (r & 3) + 8*(r >> 2) + 4*hi;
        float val = ((half*2+hh)==0 ? o0[r] : (half*2+hh)==1 ? o1[r]
                     : (half*2+hh)==2 ? o2[r] : o3[r]) * invl;
        *(bf16*)(ow + l31*128 + (((unsigned)(dcol*2)) ^ eswz)) = __float2bfloat16(val);
      }
    }
    #pragma unroll
    for (int m = 0; m < 4; ++m) {
      const int c0 = hi*32 + m*8;
      bf16x8 vv = *(const bf16x8*)(ow + l31*128 + (((unsigned)(c0*2)) ^ eswz));
      *(bf16x8*)(aop + half*64 + c0) = vv;
    }
  }
}

// --------------------------------------------------------------------- launch
extern "C" void kernel_launch(void* const* d_in, const int* in_sizes, int n_in,
                              void* d_out, int out_size, void* d_ws, size_t ws_size,
                              hipStream_t stream)
{
  const float* x    = (const float*)d_in[0];
  const float* cosb = (const float*)d_in[1];
  const float* sinb = (const float*)d_in[2];
  const float* wq   = (const float*)d_in[3];
  const float* wk   = (const float*)d_in[4];
  const float* wv   = (const float*)d_in[5];
  const float* wo   = (const float*)d_in[6];
  const float* qnw  = (const float*)d_in[7];
  const float* knw  = (const float*)d_in[8];
  float* out = (float*)d_out;

  char* ws = (char*)d_ws;
  bf16* xb    = (bf16*)(ws);                  // 32 MiB
  bf16* wqkvb = (bf16*)(ws +  33554432);      // 48 MiB [6144][4096] Wq|Wk|Wv
  bf16* wob   = (bf16*)(ws +  83886080);      // 32 MiB
  bf16* q0    = (bf16*)(ws + 117440512);      // 32 MiB [4096][4096]
  bf16* kv0   = (bf16*)(ws + 150994944);      // 16 MiB [4096][2048] K|V
  bf16* qr    = (bf16*)(ws + 167772160);      // 32 MiB (end 192 MiB)
  // ordering-safe aliases:
  bf16* vt = xb;                              // xb dead after projections
  bf16* kr = (bf16*)(ws + 8388608);           // xb+8MiB, same lifetime
  bf16* ao = q0;                              // q0 dead after q normrope

  f2b5<<<2048, 256, 0, stream>>>(x, wq, wk, wv, wo,
                                 xb, wqkvb,
                                 wqkvb + (size_t)4096*4096,
                                 wqkvb + (size_t)5120*4096,
                                 wob);

  // fused Q-proj (256 blocks) + KV-proj (256 blocks), Q first (LPT)
  qkvproj<<<512, 512, 0, stream>>>(xb, wqkvb, q0, kv0);

  // fused vtrans + q/k RMSNorm+RoPE (q scale folds 1/sqrt(HD)*log2(e))
  postproc<<<1024 + (MR*NH)/4 + (MR*NKV)/4, 256, 0, stream>>>(
      q0, kv0, qr, kr, vt, cosb, sinb, qnw, knw);

  attn_fwd<<<512, 512, 0, stream>>>(qr, kr, vt, ao);

  oproj<<<256, 512, 0, stream>>>(ao, wob, out);
}